// Round 3
// baseline (4580.486 us; speedup 1.0000x reference)
//
#include <hip/hip_runtime.h>
#include <hip/hip_cooperative_groups.h>
#include <math.h>

namespace cg = cooperative_groups;

#define Hd 128
#define Ln 64
#define Bsz 8
#define NBLK 256
#define NTHR 512

// T layout: T[((b*Ln + i)*Ln + j)*Hd + c], 16 MB in d_ws.
// Wave wv of a block handles rows k = wv + 8r (r < NRQ) of its cell.
// NRQ = per-wave valid row count rounded up to even; rows with k >= i are
// clamped to k=i-1 (finite garbage) and masked with -inf logits.

template<int NRQ>
__device__ __forceinline__ void cell_work(
    const float* __restrict__ Tb, const float* __restrict__ sW,
    float* __restrict__ sHw, float* __restrict__ sAccw, float* __restrict__ sMSw,
    int i, int j, int wv, int ln,
    float2 wlv, float2 wrv, float bl, float br, float bs,
    float ws0, float ws1, float bb0, float bb1)
{
    // ---- load left/right rows (float2 per lane, coalesced 512B/row) ----
    float2 Lr[NRQ], Rr[NRQ];
    #pragma unroll
    for (int r = 0; r < NRQ; ++r) {
        int k = wv + 8 * r;
        int kcl = k < i ? k : i - 1;
        Lr[r] = *(const float2*)(Tb + ((size_t)kcl * Ln + j) * Hd + 2 * ln);
        Rr[r] = *(const float2*)(Tb + ((size_t)(i - 1 - kcl) * Ln + (j + kcl + 1)) * Hd + 2 * ln);
    }

    // ---- dot products sl, sr (64-lane butterfly) ----
    float pl[NRQ], pr[NRQ];
    #pragma unroll
    for (int r = 0; r < NRQ; ++r) {
        pl[r] = Lr[r].x * wlv.x + Lr[r].y * wlv.y;
        pr[r] = Rr[r].x * wrv.x + Rr[r].y * wrv.y;
    }
    #pragma unroll
    for (int off = 32; off > 0; off >>= 1) {
        #pragma unroll
        for (int r = 0; r < NRQ; ++r) {
            pl[r] += __shfl_xor(pl[r], off);
            pr[r] += __shfl_xor(pr[r], off);
        }
    }

    // ---- 2-way softmax -> h_hat into wave-private LDS ----
    #pragma unroll
    for (int r = 0; r < NRQ; ++r) {
        float sl = pl[r] + bl, sr = pr[r] + br;
        float mm = fmaxf(sl, sr);
        float e0 = __expf(sl - mm), e1 = __expf(sr - mm);
        float inv = 1.f / (e0 + e1);
        float w0 = e0 * inv, w1 = e1 * inv;
        float2 hh;
        hh.x = w0 * Lr[r].x + w1 * Rr[r].x;
        hh.y = w0 * Lr[r].y + w1 * Rr[r].y;
        *(float2*)&sHw[r * Hd + 2 * ln] = hh;
    }

    // ---- matvec: lane owns cols c0=ln, c1=ln+64; swizzled w-reads ----
    const int c0 = ln, c1 = ln + 64;
    const int x0 = ln & 31;
    float acc0[NRQ], acc1[NRQ];
    #pragma unroll
    for (int r = 0; r < NRQ; ++r) { acc0[r] = 0.f; acc1[r] = 0.f; }
    const float* sW0 = &sW[c0 * Hd];
    const float* sW1 = &sW[c1 * Hd];
    #pragma unroll 8
    for (int hb = 0; hb < 32; ++hb) {
        float4 w0v = *(const float4*)&sW0[(hb ^ x0) << 2];
        float4 w1v = *(const float4*)&sW1[(hb ^ x0) << 2];
        #pragma unroll
        for (int r = 0; r < NRQ; ++r) {
            float4 hv = *(const float4*)&sHw[r * Hd + (hb << 2)];   // broadcast
            acc0[r] += hv.x * w0v.x + hv.y * w0v.y + hv.z * w0v.z + hv.w * w0v.w;
            acc1[r] += hv.x * w1v.x + hv.y * w1v.y + hv.z * w1v.z + hv.w * w1v.w;
        }
    }

    // ---- temp = relu(.+brep)+h_hat; logits; per-wave softmax partials ----
    float t0[NRQ], t1[NRQ], lg[NRQ];
    #pragma unroll
    for (int r = 0; r < NRQ; ++r) {
        float h0 = sHw[r * Hd + c0], h1 = sHw[r * Hd + c1];
        t0[r] = fmaxf(acc0[r] + bb0, 0.f) + h0;
        t1[r] = fmaxf(acc1[r] + bb1, 0.f) + h1;
        lg[r] = t0[r] * ws0 + t1[r] * ws1;
    }
    #pragma unroll
    for (int off = 32; off > 0; off >>= 1) {
        #pragma unroll
        for (int r = 0; r < NRQ; ++r) lg[r] += __shfl_xor(lg[r], off);
    }
    #pragma unroll
    for (int r = 0; r < NRQ; ++r)
        lg[r] = (wv + 8 * r < i) ? (lg[r] + bs) : -INFINITY;

    float mw = -INFINITY;
    #pragma unroll
    for (int r = 0; r < NRQ; ++r) mw = fmaxf(mw, lg[r]);
    float sw_ = 0.f, a0 = 0.f, a1 = 0.f;
    #pragma unroll
    for (int r = 0; r < NRQ; ++r) {
        float e = __expf(lg[r] - mw);
        sw_ += e; a0 += e * t0[r]; a1 += e * t1[r];
    }
    if (ln == 0) { sMSw[0] = mw; sMSw[1] = sw_; }
    sAccw[c0] = a0;
    sAccw[c1] = a1;
}

__global__ __launch_bounds__(NTHR, 2)
void glt_kernel(const float* __restrict__ wf,
                const float* __restrict__ Wl, const float* __restrict__ blp,
                const float* __restrict__ Wr, const float* __restrict__ brp,
                const float* __restrict__ Wrep, const float* __restrict__ brepp,
                const float* __restrict__ Wsv, const float* __restrict__ bsp,
                float* __restrict__ T, float* __restrict__ out)
{
    cg::grid_group grid = cg::this_grid();

    __shared__ __align__(16) float sW[Hd * Hd];   // 64 KB, transposed+swizzled
    __shared__ __align__(16) float sH[8][8][Hd];  // 32 KB
    __shared__ float sAccM[8][Hd];                // 4 KB
    __shared__ float sMS[8][2];

    const int tid = threadIdx.x;
    const int wv  = tid >> 6;
    const int ln  = tid & 63;
    const int bid = blockIdx.x;

    // ---- stage Wrep transposed + XOR-swizzled (once) ----
    #pragma unroll
    for (int it = 0; it < 8; ++it) {
        int idx4 = tid + it * NTHR;          // float4 index, 0..4095
        int h  = idx4 >> 5;
        int c4 = (idx4 & 31) << 2;
        float4 v = *(const float4*)&Wrep[h * Hd + c4];
        float vv[4] = {v.x, v.y, v.z, v.w};
        #pragma unroll
        for (int q = 0; q < 4; ++q) {
            int c = c4 + q;
            sW[c * Hd + ((((h >> 2) ^ (c & 31)) << 2) | (h & 3))] = vv[q];
        }
    }

    // ---- init T row 0 (grid-stride) ----
    for (int idx = bid * NTHR + tid; idx < Bsz * Ln * Hd; idx += NBLK * NTHR) {
        int b = idx >> 13, rest = idx & 8191;
        T[(size_t)b * (Ln * Ln * Hd) + rest] = wf[idx];
    }

    const float bl = blp[0], br = brp[0], bs = bsp[0];
    const float2 wlv = *(const float2*)&Wl[2 * ln];
    const float2 wrv = *(const float2*)&Wr[2 * ln];
    const int c0 = ln, c1 = ln + 64;
    const float ws0 = Wsv[c0], ws1 = Wsv[c1];
    const float bb0 = brepp[c0], bb1 = brepp[c1];

    grid.sync();

    for (int i = 1; i < Ln; ++i) {
        const int nj = Ln - i;
        const int ncells = Bsz * nj;
        for (int cc = bid; cc < ncells; cc += NBLK) {
            const int b = cc / nj;
            const int j = cc - b * nj;
            const float* Tb = T + (size_t)b * (Ln * Ln * Hd);

            int nv = (i - wv + 7) >> 3;         // rows with k = wv+8r < i
            if (nv > 8) nv = 8;
            const int nrq = (nv + 1) & ~1;      // round up to even

            float* sHw   = &sH[wv][0][0];
            float* sAccw = &sAccM[wv][0];
            float* sMSw  = &sMS[wv][0];

            switch (nrq) {
                case 2: cell_work<2>(Tb, sW, sHw, sAccw, sMSw, i, j, wv, ln,
                                     wlv, wrv, bl, br, bs, ws0, ws1, bb0, bb1); break;
                case 4: cell_work<4>(Tb, sW, sHw, sAccw, sMSw, i, j, wv, ln,
                                     wlv, wrv, bl, br, bs, ws0, ws1, bb0, bb1); break;
                case 6: cell_work<6>(Tb, sW, sHw, sAccw, sMSw, i, j, wv, ln,
                                     wlv, wrv, bl, br, bs, ws0, ws1, bb0, bb1); break;
                case 8: cell_work<8>(Tb, sW, sHw, sAccw, sMSw, i, j, wv, ln,
                                     wlv, wrv, bl, br, bs, ws0, ws1, bb0, bb1); break;
                default:                        // nv == 0: neutral partials
                    if (ln == 0) { sMSw[0] = -INFINITY; sMSw[1] = 0.f; }
                    sAccw[c0] = 0.f; sAccw[c1] = 0.f;
                    break;
            }
            __syncthreads();

            // ---- merge 8 waves; invalid k add (64-i)*exp(bs) to denom ----
            if (tid < Hd) {
                float M = bs;
                #pragma unroll
                for (int w = 0; w < 8; ++w) M = fmaxf(M, sMS[w][0]);
                float den = (float)nj * __expf(bs - M);
                float num = 0.f;
                #pragma unroll
                for (int w = 0; w < 8; ++w) {
                    float e = __expf(sMS[w][0] - M);
                    den += e * sMS[w][1];
                    num += e * sAccM[w][tid];
                }
                float res = num / den;
                T[(((size_t)b * Ln + i) * Ln + j) * Hd + tid] = res;
                if (i == Ln - 1) out[b * Hd + tid] = res;   // final output fold
            }
            __syncthreads();
        }
        if (i < Ln - 1) {
            __threadfence();
            grid.sync();
        }
    }
}

extern "C" void kernel_launch(void* const* d_in, const int* in_sizes, int n_in,
                              void* d_out, int out_size, void* d_ws, size_t ws_size,
                              hipStream_t stream)
{
    const float* wf   = (const float*)d_in[0];
    const float* Wl   = (const float*)d_in[2];
    const float* bl   = (const float*)d_in[3];
    const float* Wr   = (const float*)d_in[4];
    const float* br   = (const float*)d_in[5];
    const float* Wrep = (const float*)d_in[6];
    const float* brep = (const float*)d_in[7];
    const float* Ws   = (const float*)d_in[8];
    const float* bs   = (const float*)d_in[9];

    float* T   = (float*)d_ws;    // 16 MB
    float* out = (float*)d_out;

    void* args[] = {(void*)&wf, (void*)&Wl, (void*)&bl, (void*)&Wr, (void*)&br,
                    (void*)&Wrep, (void*)&brep, (void*)&Ws, (void*)&bs,
                    (void*)&T, (void*)&out};
    hipLaunchCooperativeKernel((void*)glt_kernel, dim3(NBLK), dim3(NTHR),
                               args, 0, stream);
}

// Round 4
// 1211.525 us; speedup vs baseline: 3.7808x; 3.7808x over previous
//
#include <hip/hip_runtime.h>
#include <math.h>

#define Hd 128
#define Ln 64
#define Bsz 8
#define NBLK 256
#define NTHR 512
#define SLOTS 32   // blocks per batch (NBLK / Bsz)

// d_ws layout: T[8][64][64][128] floats (16 MB), then flags int[8][64][64] (128 KB).
// Cell (b,i,j) dataflow deps (i>=2): flags (i-1,j) and (i-1,j+1) — transitively
// cover the full left column and right diagonal.

__global__ void init_kernel(const float* __restrict__ wf, float* __restrict__ T,
                            int* __restrict__ flg) {
    int idx = blockIdx.x * 256 + threadIdx.x;   // 0..65535
    int b = idx >> 13;
    int rest = idx & 8191;
    T[(size_t)b * (Ln * Ln * Hd) + rest] = wf[idx];
    if (idx < Bsz * Ln * Ln) flg[idx] = 0;
}

template<int NRQ>
__device__ __forceinline__ void cell_work(
    const float* __restrict__ Tb, const float* __restrict__ sW,
    float* __restrict__ sHw, float* __restrict__ sAccw, float* __restrict__ sMSw,
    int i, int j, int wv, int ln,
    float2 wlv, float2 wrv, float bl, float br, float bs,
    float ws0, float ws1, float bb0, float bb1)
{
    // ---- load left/right rows (float2 per lane, coalesced 512B/row) ----
    float2 Lr[NRQ], Rr[NRQ];
    #pragma unroll
    for (int r = 0; r < NRQ; ++r) {
        int k = wv + 8 * r;
        int kcl = k < i ? k : i - 1;
        Lr[r] = *(const float2*)(Tb + ((size_t)kcl * Ln + j) * Hd + 2 * ln);
        Rr[r] = *(const float2*)(Tb + ((size_t)(i - 1 - kcl) * Ln + (j + kcl + 1)) * Hd + 2 * ln);
    }

    // ---- dot products sl, sr (64-lane butterfly) ----
    float pl[NRQ], pr[NRQ];
    #pragma unroll
    for (int r = 0; r < NRQ; ++r) {
        pl[r] = Lr[r].x * wlv.x + Lr[r].y * wlv.y;
        pr[r] = Rr[r].x * wrv.x + Rr[r].y * wrv.y;
    }
    #pragma unroll
    for (int off = 32; off > 0; off >>= 1) {
        #pragma unroll
        for (int r = 0; r < NRQ; ++r) {
            pl[r] += __shfl_xor(pl[r], off);
            pr[r] += __shfl_xor(pr[r], off);
        }
    }

    // ---- 2-way softmax -> h_hat into wave-private LDS ----
    #pragma unroll
    for (int r = 0; r < NRQ; ++r) {
        float sl = pl[r] + bl, sr = pr[r] + br;
        float mm = fmaxf(sl, sr);
        float e0 = __expf(sl - mm), e1 = __expf(sr - mm);
        float inv = 1.f / (e0 + e1);
        float w0 = e0 * inv, w1 = e1 * inv;
        float2 hh;
        hh.x = w0 * Lr[r].x + w1 * Rr[r].x;
        hh.y = w0 * Lr[r].y + w1 * Rr[r].y;
        *(float2*)&sHw[r * Hd + 2 * ln] = hh;
    }

    // ---- matvec: lane owns cols c0=ln, c1=ln+64; swizzled w-reads ----
    const int c0 = ln, c1 = ln + 64;
    const int x0 = ln & 31;
    float acc0[NRQ], acc1[NRQ];
    #pragma unroll
    for (int r = 0; r < NRQ; ++r) { acc0[r] = 0.f; acc1[r] = 0.f; }
    const float* sW0 = &sW[c0 * Hd];
    const float* sW1 = &sW[c1 * Hd];
    #pragma unroll 8
    for (int hb = 0; hb < 32; ++hb) {
        float4 w0v = *(const float4*)&sW0[(hb ^ x0) << 2];
        float4 w1v = *(const float4*)&sW1[(hb ^ x0) << 2];
        #pragma unroll
        for (int r = 0; r < NRQ; ++r) {
            float4 hv = *(const float4*)&sHw[r * Hd + (hb << 2)];   // broadcast
            acc0[r] += hv.x * w0v.x + hv.y * w0v.y + hv.z * w0v.z + hv.w * w0v.w;
            acc1[r] += hv.x * w1v.x + hv.y * w1v.y + hv.z * w1v.z + hv.w * w1v.w;
        }
    }

    // ---- temp = relu(.+brep)+h_hat; logits; per-wave softmax partials ----
    float t0[NRQ], t1[NRQ], lg[NRQ];
    #pragma unroll
    for (int r = 0; r < NRQ; ++r) {
        float h0 = sHw[r * Hd + c0], h1 = sHw[r * Hd + c1];
        t0[r] = fmaxf(acc0[r] + bb0, 0.f) + h0;
        t1[r] = fmaxf(acc1[r] + bb1, 0.f) + h1;
        lg[r] = t0[r] * ws0 + t1[r] * ws1;
    }
    #pragma unroll
    for (int off = 32; off > 0; off >>= 1) {
        #pragma unroll
        for (int r = 0; r < NRQ; ++r) lg[r] += __shfl_xor(lg[r], off);
    }
    #pragma unroll
    for (int r = 0; r < NRQ; ++r)
        lg[r] = (wv + 8 * r < i) ? (lg[r] + bs) : -INFINITY;

    float mw = -INFINITY;
    #pragma unroll
    for (int r = 0; r < NRQ; ++r) mw = fmaxf(mw, lg[r]);
    float sw_ = 0.f, a0 = 0.f, a1 = 0.f;
    #pragma unroll
    for (int r = 0; r < NRQ; ++r) {
        float e = __expf(lg[r] - mw);
        sw_ += e; a0 += e * t0[r]; a1 += e * t1[r];
    }
    if (ln == 0) { sMSw[0] = mw; sMSw[1] = sw_; }
    sAccw[c0] = a0;
    sAccw[c1] = a1;
}

__global__ __launch_bounds__(NTHR, 2)
void glt_df(const float* __restrict__ Wl, const float* __restrict__ blp,
            const float* __restrict__ Wr, const float* __restrict__ brp,
            const float* __restrict__ Wrep, const float* __restrict__ brepp,
            const float* __restrict__ Wsv, const float* __restrict__ bsp,
            float* __restrict__ T, int* __restrict__ flg, float* __restrict__ out)
{
    __shared__ __align__(16) float sW[Hd * Hd];   // 64 KB, transposed+swizzled
    __shared__ __align__(16) float sH[8][8][Hd];  // 32 KB
    __shared__ float sAccM[8][Hd];                // 4 KB
    __shared__ float sMS[8][2];

    const int tid = threadIdx.x;
    const int wv  = tid >> 6;
    const int ln  = tid & 63;
    const int b   = blockIdx.x & 7;      // XCD round-robin: batch -> XCD
    const int s   = blockIdx.x >> 3;     // slot 0..31 within batch

    // ---- stage Wrep transposed + XOR-swizzled (once per block) ----
    #pragma unroll
    for (int it = 0; it < 8; ++it) {
        int idx4 = tid + it * NTHR;          // float4 index, 0..4095
        int h  = idx4 >> 5;
        int c4 = (idx4 & 31) << 2;
        float4 v = *(const float4*)&Wrep[h * Hd + c4];
        float vv[4] = {v.x, v.y, v.z, v.w};
        #pragma unroll
        for (int q = 0; q < 4; ++q) {
            int c = c4 + q;
            sW[c * Hd + ((((h >> 2) ^ (c & 31)) << 2) | (h & 3))] = vv[q];
        }
    }

    const float bl = blp[0], br = brp[0], bs = bsp[0];
    const float2 wlv = *(const float2*)&Wl[2 * ln];
    const float2 wrv = *(const float2*)&Wr[2 * ln];
    const int c0 = ln, c1 = ln + 64;
    const float ws0 = Wsv[c0], ws1 = Wsv[c1];
    const float bb0 = brepp[c0], bb1 = brepp[c1];

    const float* Tb = T + (size_t)b * (Ln * Ln * Hd);
    int* flgb = flg + b * (Ln * Ln);

    // level-sorted walk: per-batch cell index c = s + 32t, t = 0..62
    int i = 1, j = s;
    for (int t = 0; t < 63; ++t) {
        // ---- wait for the two covering deps (i>=2) ----
        if (i > 1 && tid == 0) {
            const int base = (i - 1) * Ln + j;
            while (__hip_atomic_load(&flgb[base], __ATOMIC_RELAXED,
                                     __HIP_MEMORY_SCOPE_AGENT) == 0)
                __builtin_amdgcn_s_sleep(1);
            while (__hip_atomic_load(&flgb[base + 1], __ATOMIC_RELAXED,
                                     __HIP_MEMORY_SCOPE_AGENT) == 0)
                __builtin_amdgcn_s_sleep(1);
            __threadfence();   // acquire: invalidate L1/L2 so row loads see LLC data
        }
        __syncthreads();       // deps visible; also protects sH reuse

        int nv = (i - wv + 7) >> 3;         // rows with k = wv+8r < i
        if (nv > 8) nv = 8;
        const int nrq = (nv + 1) & ~1;      // round up to even

        float* sHw   = &sH[wv][0][0];
        float* sAccw = &sAccM[wv][0];
        float* sMSw  = &sMS[wv][0];

        switch (nrq) {
            case 2: cell_work<2>(Tb, sW, sHw, sAccw, sMSw, i, j, wv, ln,
                                 wlv, wrv, bl, br, bs, ws0, ws1, bb0, bb1); break;
            case 4: cell_work<4>(Tb, sW, sHw, sAccw, sMSw, i, j, wv, ln,
                                 wlv, wrv, bl, br, bs, ws0, ws1, bb0, bb1); break;
            case 6: cell_work<6>(Tb, sW, sHw, sAccw, sMSw, i, j, wv, ln,
                                 wlv, wrv, bl, br, bs, ws0, ws1, bb0, bb1); break;
            case 8: cell_work<8>(Tb, sW, sHw, sAccw, sMSw, i, j, wv, ln,
                                 wlv, wrv, bl, br, bs, ws0, ws1, bb0, bb1); break;
            default:
                if (ln == 0) { sMSw[0] = -INFINITY; sMSw[1] = 0.f; }
                sAccw[c0] = 0.f; sAccw[c1] = 0.f;
                break;
        }
        __syncthreads();

        // ---- merge 8 waves; invalid k add (64-i)*exp(bs) to denom ----
        if (tid < Hd) {
            float M = bs;
            #pragma unroll
            for (int w = 0; w < 8; ++w) M = fmaxf(M, sMS[w][0]);
            float den = (float)(Ln - i) * __expf(bs - M);
            float num = 0.f;
            #pragma unroll
            for (int w = 0; w < 8; ++w) {
                float e = __expf(sMS[w][0] - M);
                den += e * sMS[w][1];
                num += e * sAccM[w][tid];
            }
            float res = num / den;
            T[(((size_t)b * Ln + i) * Ln + j) * Hd + tid] = res;
            if (i == Ln - 1) out[b * Hd + tid] = res;
        }
        __syncthreads();       // row stores drained (vmcnt 0 before barrier)
        if (tid == 0) {
            __threadfence();   // release: write back dirty L2 lines to LLC
            __hip_atomic_store(&flgb[i * Ln + j], 1, __ATOMIC_RELEASE,
                               __HIP_MEMORY_SCOPE_AGENT);
        }

        // ---- advance to next owned cell (level-major, stride 32) ----
        if (t < 62) {
            j += SLOTS;
            while (j >= Ln - i) { j -= Ln - i; ++i; }
        }
    }
}

extern "C" void kernel_launch(void* const* d_in, const int* in_sizes, int n_in,
                              void* d_out, int out_size, void* d_ws, size_t ws_size,
                              hipStream_t stream)
{
    const float* wf   = (const float*)d_in[0];
    const float* Wl   = (const float*)d_in[2];
    const float* bl   = (const float*)d_in[3];
    const float* Wr   = (const float*)d_in[4];
    const float* br   = (const float*)d_in[5];
    const float* Wrep = (const float*)d_in[6];
    const float* brep = (const float*)d_in[7];
    const float* Ws   = (const float*)d_in[8];
    const float* bs   = (const float*)d_in[9];

    float* T   = (float*)d_ws;                                   // 16 MB
    int*   flg = (int*)((char*)d_ws + (size_t)Bsz * Ln * Ln * Hd * 4);
    float* out = (float*)d_out;

    init_kernel<<<256, 256, 0, stream>>>(wf, T, flg);

    void* args[] = {(void*)&Wl, (void*)&bl, (void*)&Wr, (void*)&br,
                    (void*)&Wrep, (void*)&brep, (void*)&Ws, (void*)&bs,
                    (void*)&T, (void*)&flg, (void*)&out};
    hipLaunchCooperativeKernel((void*)glt_df, dim3(NBLK), dim3(NTHR),
                               args, 0, stream);
}

// Round 5
// 827.528 us; speedup vs baseline: 5.5351x; 1.4640x over previous
//
#include <hip/hip_runtime.h>
#include <math.h>

#define Hd 128
#define Ln 64
#define Bsz 8
#define NBLK 256
#define NTHR 512
#define SLOTS 32   // blocks per batch (NBLK / Bsz)

// d_ws layout: T[8][64][64][128] floats (16 MB), then flags int[8][64][64] (128 KB).
// Cell (b,i,j) dataflow deps (i>=2): flags (i-1,j) and (i-1,j+1) — transitively
// cover the full left column and right diagonal.
// All inter-block data moves through agent-scope relaxed atomics (sc1 path:
// bypasses non-coherent per-XCD L1/L2, coherence point = LLC). No threadfence.

__global__ void init_kernel(const float* __restrict__ wf, float* __restrict__ T,
                            int* __restrict__ flg) {
    int idx = blockIdx.x * 256 + threadIdx.x;   // 0..65535
    int b = idx >> 13;
    int rest = idx & 8191;
    T[(size_t)b * (Ln * Ln * Hd) + rest] = wf[idx];
    if (idx < Bsz * Ln * Ln) flg[idx] = 0;
}

__device__ __forceinline__ float2 ld_row8(const float* p) {
    unsigned long long v = __hip_atomic_load((const unsigned long long*)p,
                                             __ATOMIC_RELAXED, __HIP_MEMORY_SCOPE_AGENT);
    return __builtin_bit_cast(float2, v);
}

template<int NRQ>
__device__ __forceinline__ void cell_work(
    const float* __restrict__ Tb, const float* __restrict__ sW,
    float* __restrict__ sHw, float* __restrict__ sAccw, float* __restrict__ sMSw,
    int i, int j, int wv, int ln,
    float2 wlv, float2 wrv, float bl, float br, float bs,
    float ws0, float ws1, float bb0, float bb1)
{
    // ---- load left/right rows via agent-scope (LLC) loads, 8B per lane ----
    float2 Lr[NRQ], Rr[NRQ];
    #pragma unroll
    for (int r = 0; r < NRQ; ++r) {
        int k = wv + 8 * r;
        int kcl = k < i ? k : i - 1;
        Lr[r] = ld_row8(Tb + ((size_t)kcl * Ln + j) * Hd + 2 * ln);
        Rr[r] = ld_row8(Tb + ((size_t)(i - 1 - kcl) * Ln + (j + kcl + 1)) * Hd + 2 * ln);
    }

    // ---- dot products sl, sr (64-lane butterfly) ----
    float pl[NRQ], pr[NRQ];
    #pragma unroll
    for (int r = 0; r < NRQ; ++r) {
        pl[r] = Lr[r].x * wlv.x + Lr[r].y * wlv.y;
        pr[r] = Rr[r].x * wrv.x + Rr[r].y * wrv.y;
    }
    #pragma unroll
    for (int off = 32; off > 0; off >>= 1) {
        #pragma unroll
        for (int r = 0; r < NRQ; ++r) {
            pl[r] += __shfl_xor(pl[r], off);
            pr[r] += __shfl_xor(pr[r], off);
        }
    }

    // ---- 2-way softmax -> h_hat into wave-private LDS ----
    #pragma unroll
    for (int r = 0; r < NRQ; ++r) {
        float sl = pl[r] + bl, sr = pr[r] + br;
        float mm = fmaxf(sl, sr);
        float e0 = __expf(sl - mm), e1 = __expf(sr - mm);
        float inv = 1.f / (e0 + e1);
        float w0 = e0 * inv, w1 = e1 * inv;
        float2 hh;
        hh.x = w0 * Lr[r].x + w1 * Rr[r].x;
        hh.y = w0 * Lr[r].y + w1 * Rr[r].y;
        *(float2*)&sHw[r * Hd + 2 * ln] = hh;
    }

    // ---- matvec: lane owns cols c0=ln, c1=ln+64; swizzled w-reads ----
    const int c0 = ln, c1 = ln + 64;
    const int x0 = ln & 31;
    float acc0[NRQ], acc1[NRQ];
    #pragma unroll
    for (int r = 0; r < NRQ; ++r) { acc0[r] = 0.f; acc1[r] = 0.f; }
    const float* sW0 = &sW[c0 * Hd];
    const float* sW1 = &sW[c1 * Hd];
    #pragma unroll 8
    for (int hb = 0; hb < 32; ++hb) {
        float4 w0v = *(const float4*)&sW0[(hb ^ x0) << 2];
        float4 w1v = *(const float4*)&sW1[(hb ^ x0) << 2];
        #pragma unroll
        for (int r = 0; r < NRQ; ++r) {
            float4 hv = *(const float4*)&sHw[r * Hd + (hb << 2)];   // broadcast
            acc0[r] += hv.x * w0v.x + hv.y * w0v.y + hv.z * w0v.z + hv.w * w0v.w;
            acc1[r] += hv.x * w1v.x + hv.y * w1v.y + hv.z * w1v.z + hv.w * w1v.w;
        }
    }

    // ---- temp = relu(.+brep)+h_hat; logits; per-wave softmax partials ----
    float t0[NRQ], t1[NRQ], lg[NRQ];
    #pragma unroll
    for (int r = 0; r < NRQ; ++r) {
        float h0 = sHw[r * Hd + c0], h1 = sHw[r * Hd + c1];
        t0[r] = fmaxf(acc0[r] + bb0, 0.f) + h0;
        t1[r] = fmaxf(acc1[r] + bb1, 0.f) + h1;
        lg[r] = t0[r] * ws0 + t1[r] * ws1;
    }
    #pragma unroll
    for (int off = 32; off > 0; off >>= 1) {
        #pragma unroll
        for (int r = 0; r < NRQ; ++r) lg[r] += __shfl_xor(lg[r], off);
    }
    #pragma unroll
    for (int r = 0; r < NRQ; ++r)
        lg[r] = (wv + 8 * r < i) ? (lg[r] + bs) : -INFINITY;

    float mw = -INFINITY;
    #pragma unroll
    for (int r = 0; r < NRQ; ++r) mw = fmaxf(mw, lg[r]);
    float sw_ = 0.f, a0 = 0.f, a1 = 0.f;
    #pragma unroll
    for (int r = 0; r < NRQ; ++r) {
        float e = __expf(lg[r] - mw);
        sw_ += e; a0 += e * t0[r]; a1 += e * t1[r];
    }
    if (ln == 0) { sMSw[0] = mw; sMSw[1] = sw_; }
    sAccw[c0] = a0;
    sAccw[c1] = a1;
}

__global__ __launch_bounds__(NTHR, 2)
void glt_df(const float* __restrict__ Wl, const float* __restrict__ blp,
            const float* __restrict__ Wr, const float* __restrict__ brp,
            const float* __restrict__ Wrep, const float* __restrict__ brepp,
            const float* __restrict__ Wsv, const float* __restrict__ bsp,
            float* __restrict__ T, int* __restrict__ flg, float* __restrict__ out)
{
    __shared__ __align__(16) float sW[Hd * Hd];   // 64 KB, transposed+swizzled
    __shared__ __align__(16) float sH[8][8][Hd];  // 32 KB
    __shared__ float sAccM[8][Hd];                // 4 KB
    __shared__ float sMS[8][2];

    const int tid = threadIdx.x;
    const int wv  = tid >> 6;
    const int ln  = tid & 63;
    const int b   = blockIdx.x & 7;      // XCD round-robin heuristic (perf only)
    const int s   = blockIdx.x >> 3;     // slot 0..31 within batch

    // ---- stage Wrep transposed + XOR-swizzled; lane->h mapping:
    //      conflict-free LDS stores (32 distinct banks per half-wave) ----
    #pragma unroll
    for (int it = 0; it < 8; ++it) {
        int idx4 = tid + it * NTHR;          // 0..4095
        int h  = idx4 & 127;
        int c4 = (idx4 >> 7) << 2;           // 0,4,...,124
        float4 v = *(const float4*)&Wrep[h * Hd + c4];
        float vv[4] = {v.x, v.y, v.z, v.w};
        #pragma unroll
        for (int q = 0; q < 4; ++q) {
            int c = c4 + q;
            sW[c * Hd + ((((h >> 2) ^ (c & 31)) << 2) | (h & 3))] = vv[q];
        }
    }

    const float bl = blp[0], br = brp[0], bs = bsp[0];
    const float2 wlv = *(const float2*)&Wl[2 * ln];
    const float2 wrv = *(const float2*)&Wr[2 * ln];
    const int c0 = ln, c1 = ln + 64;
    const float ws0 = Wsv[c0], ws1 = Wsv[c1];
    const float bb0 = brepp[c0], bb1 = brepp[c1];

    const float* Tb = T + (size_t)b * (Ln * Ln * Hd);
    int* flgb = flg + b * (Ln * Ln);

    // level-sorted walk: per-batch cell index c = s + 32t, t = 0..62
    int i = 1, j = s;
    for (int t = 0; t < 63; ++t) {
        // ---- wait for the two covering deps (i>=2); agent-scope spin ----
        if (i > 1 && tid == 0) {
            const int base = (i - 1) * Ln + j;
            while (__hip_atomic_load(&flgb[base], __ATOMIC_RELAXED,
                                     __HIP_MEMORY_SCOPE_AGENT) == 0 ||
                   __hip_atomic_load(&flgb[base + 1], __ATOMIC_RELAXED,
                                     __HIP_MEMORY_SCOPE_AGENT) == 0)
                __builtin_amdgcn_s_sleep(1);
        }
        __syncthreads();       // deps observed; also protects sH/sW reuse

        int nv = (i - wv + 7) >> 3;         // rows with k = wv+8r < i
        if (nv > 8) nv = 8;
        const int nrq = (nv + 1) & ~1;      // round up to even

        float* sHw   = &sH[wv][0][0];
        float* sAccw = &sAccM[wv][0];
        float* sMSw  = &sMS[wv][0];

        switch (nrq) {
            case 2: cell_work<2>(Tb, sW, sHw, sAccw, sMSw, i, j, wv, ln,
                                 wlv, wrv, bl, br, bs, ws0, ws1, bb0, bb1); break;
            case 4: cell_work<4>(Tb, sW, sHw, sAccw, sMSw, i, j, wv, ln,
                                 wlv, wrv, bl, br, bs, ws0, ws1, bb0, bb1); break;
            case 6: cell_work<6>(Tb, sW, sHw, sAccw, sMSw, i, j, wv, ln,
                                 wlv, wrv, bl, br, bs, ws0, ws1, bb0, bb1); break;
            case 8: cell_work<8>(Tb, sW, sHw, sAccw, sMSw, i, j, wv, ln,
                                 wlv, wrv, bl, br, bs, ws0, ws1, bb0, bb1); break;
            default:
                if (ln == 0) { sMSw[0] = -INFINITY; sMSw[1] = 0.f; }
                sAccw[c0] = 0.f; sAccw[c1] = 0.f;
                break;
        }
        __syncthreads();

        // ---- merge 8 waves; invalid k add (64-i)*exp(bs) to denom;
        //      result stored agent-scope (straight to LLC) ----
        if (tid < Hd) {
            float M = bs;
            #pragma unroll
            for (int w = 0; w < 8; ++w) M = fmaxf(M, sMS[w][0]);
            float den = (float)(Ln - i) * __expf(bs - M);
            float num = 0.f;
            #pragma unroll
            for (int w = 0; w < 8; ++w) {
                float e = __expf(sMS[w][0] - M);
                den += e * sMS[w][1];
                num += e * sAccM[w][tid];
            }
            float res = num / den;
            __hip_atomic_store(&T[(((size_t)b * Ln + i) * Ln + j) * Hd + tid], res,
                               __ATOMIC_RELAXED, __HIP_MEMORY_SCOPE_AGENT);
            if (i == Ln - 1) out[b * Hd + tid] = res;
        }
        // all waves' result stores drained (vmcnt 0) before barrier completes
        __syncthreads();
        if (tid == 0) {
            asm volatile("s_waitcnt vmcnt(0)" ::: "memory");
            __hip_atomic_store(&flgb[i * Ln + j], 1, __ATOMIC_RELAXED,
                               __HIP_MEMORY_SCOPE_AGENT);
        }

        // ---- advance to next owned cell (level-major, stride 32) ----
        if (t < 62) {
            j += SLOTS;
            while (j >= Ln - i) { j -= Ln - i; ++i; }
        }
    }
}

extern "C" void kernel_launch(void* const* d_in, const int* in_sizes, int n_in,
                              void* d_out, int out_size, void* d_ws, size_t ws_size,
                              hipStream_t stream)
{
    const float* wf   = (const float*)d_in[0];
    const float* Wl   = (const float*)d_in[2];
    const float* bl   = (const float*)d_in[3];
    const float* Wr   = (const float*)d_in[4];
    const float* br   = (const float*)d_in[5];
    const float* Wrep = (const float*)d_in[6];
    const float* brep = (const float*)d_in[7];
    const float* Ws   = (const float*)d_in[8];
    const float* bs   = (const float*)d_in[9];

    float* T   = (float*)d_ws;                                   // 16 MB
    int*   flg = (int*)((char*)d_ws + (size_t)Bsz * Ln * Ln * Hd * 4);
    float* out = (float*)d_out;

    init_kernel<<<256, 256, 0, stream>>>(wf, T, flg);

    void* args[] = {(void*)&Wl, (void*)&bl, (void*)&Wr, (void*)&br,
                    (void*)&Wrep, (void*)&brep, (void*)&Ws, (void*)&bs,
                    (void*)&T, (void*)&flg, (void*)&out};
    hipLaunchCooperativeKernel((void*)glt_df, dim3(NBLK), dim3(NTHR),
                               args, 0, stream);
}

// Round 6
// 687.535 us; speedup vs baseline: 6.6622x; 1.2036x over previous
//
#include <hip/hip_runtime.h>
#include <math.h>

#define Hd 128
#define Ln 64
#define Bsz 8
#define NBLK 256
#define NTHR 512
#define SLOTS 32   // blocks per batch (NBLK / Bsz)

// d_ws layout: T[8][64][64][128] floats (16 MB), then flags int[8][64][64] (128 KB).
// Cell (b,i,j) split:
//   spec phase  : k in [1, i-2] — rows at levels <= i-2, covered transitively by
//                 flags (i-2,j) and (i-2,j+2)  (published one level earlier)
//   final phase : k = 0   (left leaf,      right = T[i-1][j+1], flag (i-1,j+1))
//                 k = i-1 (left T[i-1][j], right leaf,          flag (i-1,j)  )
// All inter-block data moves through agent-scope relaxed atomics (LLC-coherent).

__global__ void init_kernel(const float* __restrict__ wf, float* __restrict__ T,
                            int* __restrict__ flg) {
    int idx = blockIdx.x * 256 + threadIdx.x;   // 0..65535
    int b = idx >> 13;
    int rest = idx & 8191;
    T[(size_t)b * (Ln * Ln * Hd) + rest] = wf[idx];
    if (idx < Bsz * Ln * Ln) flg[idx] = 0;
}

__device__ __forceinline__ float2 ld_row8(const float* p) {
    unsigned long long v = __hip_atomic_load((const unsigned long long*)p,
                                             __ATOMIC_RELAXED, __HIP_MEMORY_SCOPE_AGENT);
    return __builtin_bit_cast(float2, v);
}

__device__ __forceinline__ void wait_flag(const int* p) {
    while (__hip_atomic_load(p, __ATOMIC_RELAXED, __HIP_MEMORY_SCOPE_AGENT) == 0)
        __builtin_amdgcn_s_sleep(1);
    asm volatile("" ::: "memory");   // compiler barrier: no load hoisting above spin
}

// ---- speculative partials: k = wv + 8r restricted to [1, i-2] ----
template<int NRQ>
__device__ __forceinline__ void spec_work(
    const float* __restrict__ Tb, const float* __restrict__ sW,
    float* __restrict__ sHw, float* __restrict__ sAccw, float* __restrict__ sMSw,
    int i, int j, int wv, int ln,
    float2 wlv, float2 wrv, float bl, float br, float bs,
    float ws0, float ws1, float bb0, float bb1)
{
    const int kmax = i - 2;
    float2 Lr[NRQ], Rr[NRQ];
    #pragma unroll
    for (int r = 0; r < NRQ; ++r) {
        int k = wv + 8 * r;
        int kcl = k < 1 ? 1 : (k > kmax ? kmax : k);
        Lr[r] = ld_row8(Tb + ((size_t)kcl * Ln + j) * Hd + 2 * ln);
        Rr[r] = ld_row8(Tb + ((size_t)(i - 1 - kcl) * Ln + (j + kcl + 1)) * Hd + 2 * ln);
    }

    float pl[NRQ], pr[NRQ];
    #pragma unroll
    for (int r = 0; r < NRQ; ++r) {
        pl[r] = Lr[r].x * wlv.x + Lr[r].y * wlv.y;
        pr[r] = Rr[r].x * wrv.x + Rr[r].y * wrv.y;
    }
    #pragma unroll
    for (int off = 32; off > 0; off >>= 1) {
        #pragma unroll
        for (int r = 0; r < NRQ; ++r) {
            pl[r] += __shfl_xor(pl[r], off);
            pr[r] += __shfl_xor(pr[r], off);
        }
    }

    #pragma unroll
    for (int r = 0; r < NRQ; ++r) {
        float sl = pl[r] + bl, sr = pr[r] + br;
        float mm = fmaxf(sl, sr);
        float e0 = __expf(sl - mm), e1 = __expf(sr - mm);
        float inv = 1.f / (e0 + e1);
        float w0 = e0 * inv, w1 = e1 * inv;
        float2 hh;
        hh.x = w0 * Lr[r].x + w1 * Rr[r].x;
        hh.y = w0 * Lr[r].y + w1 * Rr[r].y;
        *(float2*)&sHw[r * Hd + 2 * ln] = hh;
    }

    const int c0 = ln, c1 = ln + 64;
    const int x0 = ln & 31;
    float acc0[NRQ], acc1[NRQ];
    #pragma unroll
    for (int r = 0; r < NRQ; ++r) { acc0[r] = 0.f; acc1[r] = 0.f; }
    const float* sW0 = &sW[c0 * Hd];
    const float* sW1 = &sW[c1 * Hd];
    #pragma unroll 8
    for (int hb = 0; hb < 32; ++hb) {
        float4 w0v = *(const float4*)&sW0[(hb ^ x0) << 2];
        float4 w1v = *(const float4*)&sW1[(hb ^ x0) << 2];
        #pragma unroll
        for (int r = 0; r < NRQ; ++r) {
            float4 hv = *(const float4*)&sHw[r * Hd + (hb << 2)];   // broadcast
            acc0[r] += hv.x * w0v.x + hv.y * w0v.y + hv.z * w0v.z + hv.w * w0v.w;
            acc1[r] += hv.x * w1v.x + hv.y * w1v.y + hv.z * w1v.z + hv.w * w1v.w;
        }
    }

    float t0[NRQ], t1[NRQ], lg[NRQ];
    #pragma unroll
    for (int r = 0; r < NRQ; ++r) {
        float h0 = sHw[r * Hd + c0], h1 = sHw[r * Hd + c1];
        t0[r] = fmaxf(acc0[r] + bb0, 0.f) + h0;
        t1[r] = fmaxf(acc1[r] + bb1, 0.f) + h1;
        lg[r] = t0[r] * ws0 + t1[r] * ws1;
    }
    #pragma unroll
    for (int off = 32; off > 0; off >>= 1) {
        #pragma unroll
        for (int r = 0; r < NRQ; ++r) lg[r] += __shfl_xor(lg[r], off);
    }
    #pragma unroll
    for (int r = 0; r < NRQ; ++r) {
        int k = wv + 8 * r;
        lg[r] = (k >= 1 && k <= kmax) ? (lg[r] + bs) : -INFINITY;
    }

    float mw = -INFINITY;
    #pragma unroll
    for (int r = 0; r < NRQ; ++r) mw = fmaxf(mw, lg[r]);
    float mwc = fmaxf(mw, -1e30f);        // NaN-safe for fully-masked waves
    float sw_ = 0.f, a0 = 0.f, a1 = 0.f;
    #pragma unroll
    for (int r = 0; r < NRQ; ++r) {
        float e = __expf(lg[r] - mwc);
        sw_ += e; a0 += e * t0[r]; a1 += e * t1[r];
    }
    if (ln == 0) { sMSw[0] = mw; sMSw[1] = sw_; }
    sAccw[c0] = a0;
    sAccw[c1] = a1;
}

// ---- final term: one k-row handled by one wave ----
__device__ __forceinline__ void final_row(
    const float* __restrict__ lp, const float* __restrict__ rp,
    const float* __restrict__ sW,
    float* __restrict__ sHw, float* __restrict__ sAccw, float* __restrict__ sMSw,
    int ln, float2 wlv, float2 wrv, float bl, float br, float bs,
    float ws0, float ws1, float bb0, float bb1)
{
    float2 L = ld_row8(lp + 2 * ln);
    float2 R = ld_row8(rp + 2 * ln);
    float pl = L.x * wlv.x + L.y * wlv.y;
    float pr = R.x * wrv.x + R.y * wrv.y;
    #pragma unroll
    for (int off = 32; off > 0; off >>= 1) {
        pl += __shfl_xor(pl, off);
        pr += __shfl_xor(pr, off);
    }
    float sl = pl + bl, sr = pr + br;
    float mm = fmaxf(sl, sr);
    float e0 = __expf(sl - mm), e1 = __expf(sr - mm);
    float inv = 1.f / (e0 + e1);
    float w0 = e0 * inv, w1 = e1 * inv;
    float2 hh;
    hh.x = w0 * L.x + w1 * R.x;
    hh.y = w0 * L.y + w1 * R.y;
    *(float2*)&sHw[2 * ln] = hh;

    const int c0 = ln, c1 = ln + 64;
    const int x0 = ln & 31;
    float a0 = 0.f, a1 = 0.f;
    const float* sW0 = &sW[c0 * Hd];
    const float* sW1 = &sW[c1 * Hd];
    #pragma unroll 8
    for (int hb = 0; hb < 32; ++hb) {
        float4 w0v = *(const float4*)&sW0[(hb ^ x0) << 2];
        float4 w1v = *(const float4*)&sW1[(hb ^ x0) << 2];
        float4 hv = *(const float4*)&sHw[hb << 2];
        a0 += hv.x * w0v.x + hv.y * w0v.y + hv.z * w0v.z + hv.w * w0v.w;
        a1 += hv.x * w1v.x + hv.y * w1v.y + hv.z * w1v.z + hv.w * w1v.w;
    }
    float t0 = fmaxf(a0 + bb0, 0.f) + sHw[c0];
    float t1 = fmaxf(a1 + bb1, 0.f) + sHw[c1];
    float lg = t0 * ws0 + t1 * ws1;
    #pragma unroll
    for (int off = 32; off > 0; off >>= 1) lg += __shfl_xor(lg, off);
    lg += bs;
    if (ln == 0) { sMSw[0] = lg; sMSw[1] = 1.0f; }
    sAccw[c0] = t0;        // e^(lg-lg)=1
    sAccw[c1] = t1;
}

__global__ __launch_bounds__(NTHR, 2)
void glt_df(const float* __restrict__ Wl, const float* __restrict__ blp,
            const float* __restrict__ Wr, const float* __restrict__ brp,
            const float* __restrict__ Wrep, const float* __restrict__ brepp,
            const float* __restrict__ Wsv, const float* __restrict__ bsp,
            float* __restrict__ T, int* __restrict__ flg, float* __restrict__ out)
{
    __shared__ __align__(16) float sW[Hd * Hd];   // 64 KB, transposed+swizzled
    __shared__ __align__(16) float sH[8][8][Hd];  // 32 KB
    __shared__ float sAccM[10][Hd];               // 5 KB (8 spec + 2 final slots)
    __shared__ float sMS[10][2];

    const int tid = threadIdx.x;
    const int wv  = tid >> 6;
    const int ln  = tid & 63;
    const int b   = blockIdx.x & 7;      // XCD round-robin heuristic (perf only)
    const int s   = blockIdx.x >> 3;     // slot 0..31 within batch

    // ---- stage Wrep transposed + XOR-swizzled; conflict-free stores ----
    #pragma unroll
    for (int it = 0; it < 8; ++it) {
        int idx4 = tid + it * NTHR;          // 0..4095
        int h  = idx4 & 127;
        int c4 = (idx4 >> 7) << 2;
        float4 v = *(const float4*)&Wrep[h * Hd + c4];
        float vv[4] = {v.x, v.y, v.z, v.w};
        #pragma unroll
        for (int q = 0; q < 4; ++q) {
            int c = c4 + q;
            sW[c * Hd + ((((h >> 2) ^ (c & 31)) << 2) | (h & 3))] = vv[q];
        }
    }

    const float bl = blp[0], br = brp[0], bs = bsp[0];
    const float2 wlv = *(const float2*)&Wl[2 * ln];
    const float2 wrv = *(const float2*)&Wr[2 * ln];
    const int c0 = ln, c1 = ln + 64;
    const float ws0 = Wsv[c0], ws1 = Wsv[c1];
    const float bb0 = brepp[c0], bb1 = brepp[c1];

    const float* Tb = T + (size_t)b * (Ln * Ln * Hd);
    int* flgb = flg + b * (Ln * Ln);

    // level-sorted walk: per-batch cell index c = s + 32t, t = 0..62
    int i = 1, j = s;
    for (int t = 0; t < 63; ++t) {
        float* sHw   = &sH[wv][0][0];
        float* sAccw = &sAccM[wv][0];
        float* sMSw  = &sMS[wv][0];

        // ---- spec phase: k in [1, i-2], deps = flags (i-2,j),(i-2,j+2) ----
        if (i >= 3) {
            wait_flag(&flgb[(i - 2) * Ln + j]);
            wait_flag(&flgb[(i - 2) * Ln + j + 2]);
            const int nrq = ((((i - 2) >> 3) + 1) + 1) & ~1;
            switch (nrq) {
                case 2: spec_work<2>(Tb, sW, sHw, sAccw, sMSw, i, j, wv, ln,
                                     wlv, wrv, bl, br, bs, ws0, ws1, bb0, bb1); break;
                case 4: spec_work<4>(Tb, sW, sHw, sAccw, sMSw, i, j, wv, ln,
                                     wlv, wrv, bl, br, bs, ws0, ws1, bb0, bb1); break;
                case 6: spec_work<6>(Tb, sW, sHw, sAccw, sMSw, i, j, wv, ln,
                                     wlv, wrv, bl, br, bs, ws0, ws1, bb0, bb1); break;
                default: spec_work<8>(Tb, sW, sHw, sAccw, sMSw, i, j, wv, ln,
                                      wlv, wrv, bl, br, bs, ws0, ws1, bb0, bb1); break;
            }
        } else {
            if (ln == 0) { sMSw[0] = -INFINITY; sMSw[1] = 0.f; }
            sAccw[c0] = 0.f; sAccw[c1] = 0.f;
        }

        // ---- final phase: k=0 (wave 0), k=i-1 (wave 1) ----
        if (wv == 0) {
            if (i >= 2) wait_flag(&flgb[(i - 1) * Ln + j + 1]);
            final_row(Tb + (size_t)j * Hd,                             // T[0][j]
                      Tb + ((size_t)(i - 1) * Ln + (j + 1)) * Hd,      // T[i-1][j+1]
                      sW, sHw, &sAccM[8][0], &sMS[8][0], ln,
                      wlv, wrv, bl, br, bs, ws0, ws1, bb0, bb1);
        } else if (wv == 1) {
            if (i >= 2) {
                wait_flag(&flgb[(i - 1) * Ln + j]);
                final_row(Tb + ((size_t)(i - 1) * Ln + j) * Hd,        // T[i-1][j]
                          Tb + (size_t)(j + i) * Hd,                   // T[0][j+i]
                          sW, sHw, &sAccM[9][0], &sMS[9][0], ln,
                          wlv, wrv, bl, br, bs, ws0, ws1, bb0, bb1);
            } else {
                if (ln == 0) { sMS[9][0] = -INFINITY; sMS[9][1] = 0.f; }
                sAccM[9][c0] = 0.f; sAccM[9][c1] = 0.f;
            }
        }
        __syncthreads();

        // ---- merge 10 slots; invalid k add (64-i)*exp(bs) to denom ----
        if (tid < Hd) {
            float M = bs;
            #pragma unroll
            for (int w = 0; w < 10; ++w) M = fmaxf(M, sMS[w][0]);
            float den = (float)(Ln - i) * __expf(bs - M);
            float num = 0.f;
            #pragma unroll
            for (int w = 0; w < 10; ++w) {
                float e = __expf(sMS[w][0] - M);
                den += e * sMS[w][1];
                num += e * sAccM[w][tid];
            }
            float res = num / den;
            __hip_atomic_store(&T[(((size_t)b * Ln + i) * Ln + j) * Hd + tid], res,
                               __ATOMIC_RELAXED, __HIP_MEMORY_SCOPE_AGENT);
            if (i == Ln - 1) out[b * Hd + tid] = res;
        }
        // per-wave vmcnt(0) before s_barrier drains all result stores
        __syncthreads();
        if (tid == 0)
            __hip_atomic_store(&flgb[i * Ln + j], 1, __ATOMIC_RELAXED,
                               __HIP_MEMORY_SCOPE_AGENT);

        // ---- advance to next owned cell (level-major, stride 32) ----
        if (t < 62) {
            j += SLOTS;
            while (j >= Ln - i) { j -= Ln - i; ++i; }
        }
    }
}

extern "C" void kernel_launch(void* const* d_in, const int* in_sizes, int n_in,
                              void* d_out, int out_size, void* d_ws, size_t ws_size,
                              hipStream_t stream)
{
    const float* wf   = (const float*)d_in[0];
    const float* Wl   = (const float*)d_in[2];
    const float* bl   = (const float*)d_in[3];
    const float* Wr   = (const float*)d_in[4];
    const float* br   = (const float*)d_in[5];
    const float* Wrep = (const float*)d_in[6];
    const float* brep = (const float*)d_in[7];
    const float* Ws   = (const float*)d_in[8];
    const float* bs   = (const float*)d_in[9];

    float* T   = (float*)d_ws;                                   // 16 MB
    int*   flg = (int*)((char*)d_ws + (size_t)Bsz * Ln * Ln * Hd * 4);
    float* out = (float*)d_out;

    init_kernel<<<256, 256, 0, stream>>>(wf, T, flg);

    void* args[] = {(void*)&Wl, (void*)&bl, (void*)&Wr, (void*)&br,
                    (void*)&Wrep, (void*)&brep, (void*)&Ws, (void*)&bs,
                    (void*)&T, (void*)&flg, (void*)&out};
    hipLaunchCooperativeKernel((void*)glt_df, dim3(NBLK), dim3(NTHR),
                               args, 0, stream);
}

// Round 8
// 597.658 us; speedup vs baseline: 7.6641x; 1.1504x over previous
//
#include <hip/hip_runtime.h>
#include <math.h>

#define Hd 128
#define Ln 64
#define Bsz 8
#define NBLK 256
#define NTHR 512
#define SLOTS 32   // blocks per batch

// d_ws: T[8][64][64][128] f32 (16MB) + flags int[8][64][64] (128KB).
// Deps of cell (i,j): flags (i-1,j) and (i-1,j+1) (transitive cover).
// Matvec temp = relu(Hhat@Wrep+brep)+Hhat on MFMA with EXACT 3-way bf16 split
// (x = x0+x1+x2 captures the full f32 mantissa; 6 cross terms -> ~2^-24 error).
// Wrep is held in registers as per-wave B-fragments (cols 16wv..16wv+15).

typedef __attribute__((ext_vector_type(8))) short short8v;
typedef __attribute__((ext_vector_type(4))) float f32x4;

__global__ void init_kernel(const float* __restrict__ wf, float* __restrict__ T,
                            int* __restrict__ flg) {
    int idx = blockIdx.x * 256 + threadIdx.x;   // 0..65535
    int b = idx >> 13;
    int rest = idx & 8191;
    T[(size_t)b * (Ln * Ln * Hd) + rest] = wf[idx];
    if (idx < Bsz * Ln * Ln) flg[idx] = 0;
}

__device__ __forceinline__ float2 ld_row8(const float* p) {
    unsigned long long v = __hip_atomic_load((const unsigned long long*)p,
                                             __ATOMIC_RELAXED, __HIP_MEMORY_SCOPE_AGENT);
    return __builtin_bit_cast(float2, v);
}

__device__ __forceinline__ void wait_flag(const int* p) {
    while (__hip_atomic_load(p, __ATOMIC_RELAXED, __HIP_MEMORY_SCOPE_AGENT) == 0)
        __builtin_amdgcn_s_sleep(1);
    asm volatile("" ::: "memory");
}

// exact 3-way bf16 decomposition: x == bf(a0)+bf(a1)+bf(a2) (24 mantissa bits)
__device__ __forceinline__ void bf_split3(float x, unsigned short& a0,
                                          unsigned short& a1, unsigned short& a2) {
    unsigned u0 = __builtin_bit_cast(unsigned, x);
    a0 = (unsigned short)(u0 >> 16);
    float f0 = __builtin_bit_cast(float, u0 & 0xffff0000u);
    float r1 = x - f0;                       // exact
    unsigned u1 = __builtin_bit_cast(unsigned, r1);
    a1 = (unsigned short)(u1 >> 16);
    float f1 = __builtin_bit_cast(float, u1 & 0xffff0000u);
    float r2 = r1 - f1;                      // exact, bf16-representable
    a2 = (unsigned short)(__builtin_bit_cast(unsigned, r2) >> 16);
}

__device__ __forceinline__ float bfval(unsigned short v) {
    return __builtin_bit_cast(float, ((unsigned)v) << 16);
}

// A-read: row = 16ch+(ln&15), k-block idx16 = (4SK + (ln>>4)) ^ (row&15)  [swizzle]
#define KSTEP(SK, B0, B1, B2)                                                   \
    {                                                                           \
        int off = ((16 * ch + (ln & 15)) << 7) +                                \
                  ((((SK << 2) + (ln >> 4)) ^ (ln & 15)) << 3);                 \
        short8v a0 = *(const short8v*)&sH0[off];                                \
        short8v a1 = *(const short8v*)&sH1[off];                                \
        short8v a2 = *(const short8v*)&sH2[off];                                \
        acc = __builtin_amdgcn_mfma_f32_16x16x32_bf16(a0, B0, acc, 0, 0, 0);    \
        acc = __builtin_amdgcn_mfma_f32_16x16x32_bf16(a0, B1, acc, 0, 0, 0);    \
        acc = __builtin_amdgcn_mfma_f32_16x16x32_bf16(a1, B0, acc, 0, 0, 0);    \
        acc = __builtin_amdgcn_mfma_f32_16x16x32_bf16(a0, B2, acc, 0, 0, 0);    \
        acc = __builtin_amdgcn_mfma_f32_16x16x32_bf16(a1, B1, acc, 0, 0, 0);    \
        acc = __builtin_amdgcn_mfma_f32_16x16x32_bf16(a2, B0, acc, 0, 0, 0);    \
    }

template<int NCH>
__device__ __forceinline__ void do_cell(
    int i, int jj, int b, int wv, int ln, int tid,
    const float* __restrict__ Tb, float* __restrict__ T, float* __restrict__ out,
    int* __restrict__ flgb,
    unsigned short* __restrict__ sH0, unsigned short* __restrict__ sH1,
    unsigned short* __restrict__ sH2,
    float (*part)[Ln], float* __restrict__ sER,
    const short8v (&B0)[4], const short8v (&B1)[4], const short8v (&B2)[4],
    float2 wlv, float2 wrv, float bl, float br, float bs, float wsc, float bbc)
{
    // ---- wait for the two covering deps ----
    if (i >= 2) {
        wait_flag(&flgb[(i - 1) * Ln + jj]);
        wait_flag(&flgb[(i - 1) * Ln + jj + 1]);
    }

    // ---- phase A: 64 rows (k>=i duplicates row i-1; masked via sER=0) ----
    float2 Lr[8], Rr[8];
    #pragma unroll
    for (int r = 0; r < 8; ++r) {
        int k = wv + 8 * r;
        int kcl = k < i ? k : i - 1;
        Lr[r] = ld_row8(Tb + ((size_t)kcl * Ln + jj) * Hd + 2 * ln);
        Rr[r] = ld_row8(Tb + ((size_t)(i - 1 - kcl) * Ln + (jj + kcl + 1)) * Hd + 2 * ln);
    }
    float pl[8], pr[8];
    #pragma unroll
    for (int r = 0; r < 8; ++r) {
        pl[r] = Lr[r].x * wlv.x + Lr[r].y * wlv.y;
        pr[r] = Rr[r].x * wrv.x + Rr[r].y * wrv.y;
    }
    #pragma unroll
    for (int off2 = 32; off2 > 0; off2 >>= 1) {
        #pragma unroll
        for (int r = 0; r < 8; ++r) {
            pl[r] += __shfl_xor(pl[r], off2);
            pr[r] += __shfl_xor(pr[r], off2);
        }
    }
    #pragma unroll
    for (int r = 0; r < 8; ++r) {
        int k = wv + 8 * r;
        float sl = pl[r] + bl, sr2 = pr[r] + br;
        float mm = fmaxf(sl, sr2);
        float e0 = __expf(sl - mm), e1 = __expf(sr2 - mm);
        float inv = 1.f / (e0 + e1);
        float w0 = e0 * inv, w1 = e1 * inv;
        float h0 = w0 * Lr[r].x + w1 * Rr[r].x;
        float h1 = w0 * Lr[r].y + w1 * Rr[r].y;
        unsigned short x0, x1, x2, y0, y1, y2;
        bf_split3(h0, x0, x1, x2);
        bf_split3(h1, y0, y1, y2);
        // cols 2ln,2ln+1 -> 16B-block (ln>>2) XOR-swizzled by row
        int off = (k << 7) + ((((ln >> 2)) ^ (k & 15)) << 3) + ((2 * ln) & 7);
        *(unsigned*)&sH0[off] = (unsigned)x0 | ((unsigned)y0 << 16);
        *(unsigned*)&sH1[off] = (unsigned)x1 | ((unsigned)y1 << 16);
        *(unsigned*)&sH2[off] = (unsigned)x2 | ((unsigned)y2 << 16);
    }
    __syncthreads();

    // ---- MFMA matvec: wave owns cols [16wv,16wv+16), chunks of 16 rows ----
    const int colc = 16 * wv + (ln & 15);
    float tmp[NCH][4];
    #pragma unroll
    for (int ch = 0; ch < NCH; ++ch) {
        f32x4 acc = {0.f, 0.f, 0.f, 0.f};
        KSTEP(0, B0[0], B1[0], B2[0])
        KSTEP(1, B0[1], B1[1], B2[1])
        KSTEP(2, B0[2], B1[2], B2[2])
        KSTEP(3, B0[3], B1[3], B2[3])
        float p[4];
        #pragma unroll
        for (int q = 0; q < 4; ++q) {
            int row = 16 * ch + (ln >> 4) * 4 + q;   // C/D: col=lane&15, row=(lane>>4)*4+reg
            int offh = (row << 7) + (((colc >> 3) ^ (row & 15)) << 3) + (colc & 7);
            float h = (bfval(sH0[offh]) + bfval(sH1[offh])) + bfval(sH2[offh]); // exact
            float t = fmaxf(acc[q] + bbc, 0.f) + h;
            tmp[ch][q] = t;
            p[q] = t * wsc;
        }
        #pragma unroll
        for (int off2 = 1; off2 <= 8; off2 <<= 1) {
            #pragma unroll
            for (int q = 0; q < 4; ++q) p[q] += __shfl_xor(p[q], off2);
        }
        if ((ln & 15) == 0) {
            #pragma unroll
            for (int q = 0; q < 4; ++q)
                part[wv][16 * ch + (ln >> 4) * 4 + q] = p[q];
        }
    }
    __syncthreads();

    // ---- softmax over k (wave 0); invalid k add (64-i)*exp(bs) to denom ----
    if (wv == 0) {
        float lgv = -INFINITY;
        if (ln < i) {
            float ssum = part[0][ln];
            #pragma unroll
            for (int w = 1; w < 8; ++w) ssum += part[w][ln];
            lgv = ssum + bs;
        }
        float M = lgv;
        #pragma unroll
        for (int off2 = 32; off2 > 0; off2 >>= 1) M = fmaxf(M, __shfl_xor(M, off2));
        M = fmaxf(M, bs);
        float e = (ln < i) ? __expf(lgv - M) : 0.f;
        float S = e;
        #pragma unroll
        for (int off2 = 32; off2 > 0; off2 >>= 1) S += __shfl_xor(S, off2);
        sER[ln] = e;
        if (ln == 0) sER[64] = S + (float)(Ln - i) * __expf(bs - M);
    }
    __syncthreads();

    // ---- weighted sum over k; store result row ----
    float v = 0.f;
    #pragma unroll
    for (int ch = 0; ch < NCH; ++ch) {
        #pragma unroll
        for (int q = 0; q < 4; ++q)
            v += sER[16 * ch + (ln >> 4) * 4 + q] * tmp[ch][q];
    }
    v += __shfl_xor(v, 16);
    v += __shfl_xor(v, 32);
    if (ln < 16) {
        float res = v / sER[64];
        __hip_atomic_store(&T[(((size_t)b * Ln + i) * Ln + jj) * Hd + colc], res,
                           __ATOMIC_RELAXED, __HIP_MEMORY_SCOPE_AGENT);
        if (i == Ln - 1) out[b * Hd + colc] = res;
    }
    __syncthreads();   // per-wave vmcnt(0) before s_barrier drains result stores
    if (tid == 0)
        __hip_atomic_store(&flgb[i * Ln + jj], 1, __ATOMIC_RELAXED,
                           __HIP_MEMORY_SCOPE_AGENT);
}

__global__ __launch_bounds__(NTHR, 2)
void glt_df(const float* __restrict__ Wl, const float* __restrict__ blp,
            const float* __restrict__ Wr, const float* __restrict__ brp,
            const float* __restrict__ Wrep, const float* __restrict__ brepp,
            const float* __restrict__ Wsv, const float* __restrict__ bsp,
            float* __restrict__ T, int* __restrict__ flg, float* __restrict__ out)
{
    __shared__ __align__(16) unsigned short sH0[Ln * Hd];   // 16 KB
    __shared__ __align__(16) unsigned short sH1[Ln * Hd];   // 16 KB
    __shared__ __align__(16) unsigned short sH2[Ln * Hd];   // 16 KB
    __shared__ float part[8][Ln];                           // 2 KB
    __shared__ float sER[68];

    const int tid = threadIdx.x;
    const int wv  = tid >> 6;
    const int ln  = tid & 63;
    const int b   = blockIdx.x & 7;      // XCD round-robin: batch -> XCD
    const int s   = blockIdx.x >> 3;     // slot 0..31 within batch

    // ---- B-fragments: Wrep cols [16wv,16wv+16) exact 3-way bf16, registers ----
    const int bcol = 16 * wv + (ln & 15);
    short8v B0[4], B1[4], B2[4];
    #pragma unroll
    for (int sk = 0; sk < 4; ++sk) {
        #pragma unroll
        for (int jx = 0; jx < 8; ++jx) {
            int k = 32 * sk + (ln >> 4) * 8 + jx;   // same k-map as A (consistent)
            float w = Wrep[k * Hd + bcol];
            unsigned short w0, w1, w2;
            bf_split3(w, w0, w1, w2);
            B0[sk][jx] = (short)w0;
            B1[sk][jx] = (short)w1;
            B2[sk][jx] = (short)w2;
        }
    }

    const float bl = blp[0], br = brp[0], bs = bsp[0];
    const float2 wlv = *(const float2*)&Wl[2 * ln];
    const float2 wrv = *(const float2*)&Wr[2 * ln];
    const float wsc = Wsv[bcol];
    const float bbc = brepp[bcol];

    const float* Tb = T + (size_t)b * (Ln * Ln * Hd);
    int* flgb = flg + b * (Ln * Ln);

    // ---- level-major walk: per-batch cell index c = s + 32t, t = 0..62 ----
    int i = 1, jj = s;
    while (jj >= Ln - i) { jj -= Ln - i; ++i; }
    for (int t = 0; t < 63; ++t) {
        switch ((i + 15) >> 4) {
            case 1: do_cell<1>(i, jj, b, wv, ln, tid, Tb, T, out, flgb,
                               sH0, sH1, sH2, part, sER, B0, B1, B2,
                               wlv, wrv, bl, br, bs, wsc, bbc); break;
            case 2: do_cell<2>(i, jj, b, wv, ln, tid, Tb, T, out, flgb,
                               sH0, sH1, sH2, part, sER, B0, B1, B2,
                               wlv, wrv, bl, br, bs, wsc, bbc); break;
            case 3: do_cell<3>(i, jj, b, wv, ln, tid, Tb, T, out, flgb,
                               sH0, sH1, sH2, part, sER, B0, B1, B2,
                               wlv, wrv, bl, br, bs, wsc, bbc); break;
            default: do_cell<4>(i, jj, b, wv, ln, tid, Tb, T, out, flgb,
                                sH0, sH1, sH2, part, sER, B0, B1, B2,
                                wlv, wrv, bl, br, bs, wsc, bbc); break;
        }
        if (t < 62) {
            jj += SLOTS;
            while (jj >= Ln - i) { jj -= Ln - i; ++i; }
        }
    }
}

extern "C" void kernel_launch(void* const* d_in, const int* in_sizes, int n_in,
                              void* d_out, int out_size, void* d_ws, size_t ws_size,
                              hipStream_t stream)
{
    const float* wf   = (const float*)d_in[0];
    const float* Wl   = (const float*)d_in[2];
    const float* bl   = (const float*)d_in[3];
    const float* Wr   = (const float*)d_in[4];
    const float* br   = (const float*)d_in[5];
    const float* Wrep = (const float*)d_in[6];
    const float* brep = (const float*)d_in[7];
    const float* Ws   = (const float*)d_in[8];
    const float* bs   = (const float*)d_in[9];

    float* T   = (float*)d_ws;                                   // 16 MB
    int*   flg = (int*)((char*)d_ws + (size_t)Bsz * Ln * Ln * Hd * 4);
    float* out = (float*)d_out;

    init_kernel<<<256, 256, 0, stream>>>(wf, T, flg);

    void* args[] = {(void*)&Wl, (void*)&bl, (void*)&Wr, (void*)&br,
                    (void*)&Wrep, (void*)&brep, (void*)&Ws, (void*)&bs,
                    (void*)&T, (void*)&flg, (void*)&out};
    hipLaunchCooperativeKernel((void*)glt_df, dim3(NBLK), dim3(NTHR),
                               args, 0, stream);
}